// Round 1
// baseline (74.260 us; speedup 1.0000x reference)
//
#include <hip/hip_runtime.h>

#define B_  32
#define C_  256
#define HID 64
#define H_  64
#define W_  64
#define HW  4096
#define F_  4

// ---------------- Kernel 1: spectral[b,c,f] = sum_{h,w} x[b,c,h,w]*basis[f,h,w]
// basis f0 = r0[h]*r0[w], f1 = r0[h]*r1[w], f2 = r1[h]*r0[w], f3 = r1[h]*r1[w]
// r0[j] = cos(pi*j/128)*0.125, r1[j] = cos(3*pi*j/128)*sqrt(2/64)
__global__ __launch_bounds__(256) void spectral_kernel(
        const float* __restrict__ x, float* __restrict__ spectral) {
    const int plane = blockIdx.x;               // b*C + c
    const int t = threadIdx.x;                  // 0..255

    __shared__ float r0[W_], r1[W_];
    if (t < 64) {
        float fh = (float)t;
        r0[t] = cosf(fh * 0.02454369260617026f) * 0.125f;              // pi/128
        r1[t] = cosf(fh * 0.07363107781851077f) * 0.17677669529663689f; // 3pi/128, sqrt(2/64)
    }
    __syncthreads();

    const float4* xv = (const float4*)(x + (size_t)plane * HW);
    float f0 = 0.f, f1 = 0.f, f2 = 0.f, f3 = 0.f;

    #pragma unroll
    for (int q = 0; q < 4; ++q) {
        int v = q * 256 + t;              // float4 index within plane (0..1023)
        float4 d = xv[v];                 // coalesced: lane-consecutive 16B
        int h  = v >> 4;                  // 16 float4 per row
        int wb = (v & 15) << 2;
        float r0h = r0[h], r1h = r1[h];
        float e, t0, t1;
        e = d.x; t0 = e * r0[wb+0]; t1 = e * r1[wb+0];
        f0 += r0h*t0; f1 += r0h*t1; f2 += r1h*t0; f3 += r1h*t1;
        e = d.y; t0 = e * r0[wb+1]; t1 = e * r1[wb+1];
        f0 += r0h*t0; f1 += r0h*t1; f2 += r1h*t0; f3 += r1h*t1;
        e = d.z; t0 = e * r0[wb+2]; t1 = e * r1[wb+2];
        f0 += r0h*t0; f1 += r0h*t1; f2 += r1h*t0; f3 += r1h*t1;
        e = d.w; t0 = e * r0[wb+3]; t1 = e * r1[wb+3];
        f0 += r0h*t0; f1 += r0h*t1; f2 += r1h*t0; f3 += r1h*t1;
    }

    // wave (64-lane) reduction
    #pragma unroll
    for (int off = 32; off >= 1; off >>= 1) {
        f0 += __shfl_down(f0, off);
        f1 += __shfl_down(f1, off);
        f2 += __shfl_down(f2, off);
        f3 += __shfl_down(f3, off);
    }
    __shared__ float part[4][F_];
    int wave = t >> 6, lane = t & 63;
    if (lane == 0) { part[wave][0]=f0; part[wave][1]=f1; part[wave][2]=f2; part[wave][3]=f3; }
    __syncthreads();
    if (t == 0) {
        float4 s;
        s.x = part[0][0]+part[1][0]+part[2][0]+part[3][0];
        s.y = part[0][1]+part[1][1]+part[2][1]+part[3][1];
        s.z = part[0][2]+part[1][2]+part[2][2]+part[3][2];
        s.w = part[0][3]+part[1][3]+part[2][3]+part[3][3];
        ((float4*)spectral)[plane] = s;
    }
}

// ---------------- Kernel 2: per-batch MLP + sigmoid gate
// y[h,f]  = relu(sum_c spectral[b,c,f] * w1[h,c])
// y2[c,f] = sum_h y[h,f] * w2[c,h];  gate[b,c] = sigmoid(mean_f y2)
__global__ __launch_bounds__(256) void gate_kernel(
        const float* __restrict__ spectral, const float* __restrict__ w1,
        const float* __restrict__ w2, float* __restrict__ gate) {
    const int b = blockIdx.x;
    const int t = threadIdx.x;

    __shared__ float s[C_][F_];     // 4 KB
    __shared__ float y[HID][F_];    // 1 KB

    // load spectral[b] (256x4 floats): thread t loads row t as float4
    ((float4*)&s[0][0])[t] = ((const float4*)(spectral + (size_t)b * C_ * F_))[t];
    __syncthreads();

    // fc1 + relu: thread t -> (h = t/4, f = t%4)
    {
        int h = t >> 2, f = t & 3;
        const float* w1r = w1 + h * C_;
        float acc = 0.f;
        #pragma unroll 8
        for (int c = 0; c < C_; ++c) acc += s[c][f] * w1r[c];
        y[h][f] = fmaxf(acc, 0.f);
    }
    __syncthreads();

    // fc2 + mean + sigmoid: thread t -> channel c
    {
        int c = t;
        const float* w2r = w2 + c * HID;
        float a0=0.f, a1=0.f, a2=0.f, a3=0.f;
        #pragma unroll 8
        for (int h = 0; h < HID; ++h) {
            float wv = w2r[h];
            a0 += y[h][0]*wv; a1 += y[h][1]*wv; a2 += y[h][2]*wv; a3 += y[h][3]*wv;
        }
        float m = (a0 + a1 + a2 + a3) * 0.25f;
        gate[b * C_ + c] = 1.f / (1.f + __expf(-m) );
    }
}

// ---------------- Kernel 3: out = x * gate[b,c]
__global__ __launch_bounds__(256) void scale_kernel(
        const float* __restrict__ x, const float* __restrict__ gate,
        float* __restrict__ out, long long n4) {
    long long i = (long long)blockIdx.x * 256 + threadIdx.x;
    const long long stride = (long long)gridDim.x * 256;
    for (; i < n4; i += stride) {
        float4 v = ((const float4*)x)[i];
        float g = gate[i >> 10];     // 1024 float4 per (b,c) plane
        v.x *= g; v.y *= g; v.z *= g; v.w *= g;
        ((float4*)out)[i] = v;
    }
}

extern "C" void kernel_launch(void* const* d_in, const int* in_sizes, int n_in,
                              void* d_out, int out_size, void* d_ws, size_t ws_size,
                              hipStream_t stream) {
    const float* x  = (const float*)d_in[0];
    const float* w1 = (const float*)d_in[1];
    const float* w2 = (const float*)d_in[2];
    float* out = (float*)d_out;

    float* spectral = (float*)d_ws;                         // B*C*F = 32768 floats
    float* gate     = (float*)d_ws + (size_t)B_ * C_ * F_;  // B*C   = 8192 floats

    spectral_kernel<<<B_ * C_, 256, 0, stream>>>(x, spectral);
    gate_kernel<<<B_, 256, 0, stream>>>(spectral, w1, w2, gate);

    const long long n4 = (long long)B_ * C_ * HW / 4;       // 8388608
    scale_kernel<<<2048, 256, 0, stream>>>(x, gate, out, n4);
}

// Round 3
// 72.868 us; speedup vs baseline: 1.0191x; 1.0191x over previous
//
#include <hip/hip_runtime.h>

#define B_  32
#define C_  256
#define HID 64
#define H_  64
#define W_  64
#define HW  4096
#define F_  4

typedef float fvec4 __attribute__((ext_vector_type(4)));

// ---------------- Kernel 1: spectral[b,c,f] = sum_{h,w} x[b,c,h,w]*basis[f,h,w]
// basis f0 = r0[h]*r0[w], f1 = r0[h]*r1[w], f2 = r1[h]*r0[w], f3 = r1[h]*r1[w]
// r0[j] = cos(pi*j/128)*0.125, r1[j] = cos(3*pi*j/128)*sqrt(2/64)
__global__ __launch_bounds__(256) void spectral_kernel(
        const float* __restrict__ x, float* __restrict__ spectral) {
    const int plane = blockIdx.x;               // b*C + c
    const int t = threadIdx.x;                  // 0..255

    __shared__ float r0[W_], r1[W_];
    if (t < 64) {
        float fh = (float)t;
        r0[t] = cosf(fh * 0.02454369260617026f) * 0.125f;              // pi/128
        r1[t] = cosf(fh * 0.07363107781851077f) * 0.17677669529663689f; // 3pi/128, sqrt(2/64)
    }
    __syncthreads();

    const float4* xv = (const float4*)(x + (size_t)plane * HW);
    float f0 = 0.f, f1 = 0.f, f2 = 0.f, f3 = 0.f;

    #pragma unroll
    for (int q = 0; q < 4; ++q) {
        int v = q * 256 + t;              // float4 index within plane (0..1023)
        float4 d = xv[v];                 // coalesced: lane-consecutive 16B
        int h  = v >> 4;                  // 16 float4 per row
        int wb = (v & 15) << 2;
        float r0h = r0[h], r1h = r1[h];
        float e, t0, t1;
        e = d.x; t0 = e * r0[wb+0]; t1 = e * r1[wb+0];
        f0 += r0h*t0; f1 += r0h*t1; f2 += r1h*t0; f3 += r1h*t1;
        e = d.y; t0 = e * r0[wb+1]; t1 = e * r1[wb+1];
        f0 += r0h*t0; f1 += r0h*t1; f2 += r1h*t0; f3 += r1h*t1;
        e = d.z; t0 = e * r0[wb+2]; t1 = e * r1[wb+2];
        f0 += r0h*t0; f1 += r0h*t1; f2 += r1h*t0; f3 += r1h*t1;
        e = d.w; t0 = e * r0[wb+3]; t1 = e * r1[wb+3];
        f0 += r0h*t0; f1 += r0h*t1; f2 += r1h*t0; f3 += r1h*t1;
    }

    // wave (64-lane) reduction
    #pragma unroll
    for (int off = 32; off >= 1; off >>= 1) {
        f0 += __shfl_down(f0, off);
        f1 += __shfl_down(f1, off);
        f2 += __shfl_down(f2, off);
        f3 += __shfl_down(f3, off);
    }
    __shared__ float part[4][F_];
    int wave = t >> 6, lane = t & 63;
    if (lane == 0) { part[wave][0]=f0; part[wave][1]=f1; part[wave][2]=f2; part[wave][3]=f3; }
    __syncthreads();
    if (t == 0) {
        float4 s;
        s.x = part[0][0]+part[1][0]+part[2][0]+part[3][0];
        s.y = part[0][1]+part[1][1]+part[2][1]+part[3][1];
        s.z = part[0][2]+part[1][2]+part[2][2]+part[3][2];
        s.w = part[0][3]+part[1][3]+part[2][3]+part[3][3];
        ((float4*)spectral)[plane] = s;
    }
}

// ---------------- Kernel 2: per-batch MLP + sigmoid gate
// y[h,f]  = relu(sum_c spectral[b,c,f] * w1[h,c])
// y2[c,f] = sum_h y[h,f] * w2[c,h];  gate[b,c] = sigmoid(mean_f y2)
__global__ __launch_bounds__(256) void gate_kernel(
        const float* __restrict__ spectral, const float* __restrict__ w1,
        const float* __restrict__ w2, float* __restrict__ gate) {
    const int b = blockIdx.x;
    const int t = threadIdx.x;

    __shared__ float s[C_][F_];     // 4 KB
    __shared__ float y[HID][F_];    // 1 KB

    // load spectral[b] (256x4 floats): thread t loads row t as float4
    ((float4*)&s[0][0])[t] = ((const float4*)(spectral + (size_t)b * C_ * F_))[t];
    __syncthreads();

    // fc1 + relu: thread t -> (h = t/4, f = t%4); 4 accumulators break the chain
    {
        int h = t >> 2, f = t & 3;
        const float* w1r = w1 + h * C_;
        float a0 = 0.f, a1 = 0.f, a2 = 0.f, a3 = 0.f;
        #pragma unroll 4
        for (int c = 0; c < C_; c += 4) {
            a0 += s[c+0][f] * w1r[c+0];
            a1 += s[c+1][f] * w1r[c+1];
            a2 += s[c+2][f] * w1r[c+2];
            a3 += s[c+3][f] * w1r[c+3];
        }
        y[h][f] = fmaxf((a0 + a1) + (a2 + a3), 0.f);
    }
    __syncthreads();

    // fc2 + mean + sigmoid: thread t -> channel c
    {
        int c = t;
        const float* w2r = w2 + c * HID;
        float a0=0.f, a1=0.f, a2=0.f, a3=0.f;
        #pragma unroll 8
        for (int h = 0; h < HID; ++h) {
            float wv = w2r[h];
            a0 += y[h][0]*wv; a1 += y[h][1]*wv; a2 += y[h][2]*wv; a3 += y[h][3]*wv;
        }
        float m = (a0 + a1 + a2 + a3) * 0.25f;
        gate[b * C_ + c] = 1.f / (1.f + __expf(-m) );
    }
}

// ---------------- Kernel 3: out = x * gate[b,c]
// x should be L3-resident after K1; nontemporal stores keep it that way.
__global__ __launch_bounds__(256) void scale_kernel(
        const float* __restrict__ x, const float* __restrict__ gate,
        float* __restrict__ out, long long n4) {
    long long i = (long long)blockIdx.x * 256 + threadIdx.x;
    const long long stride = (long long)gridDim.x * 256;
    for (; i < n4; i += stride) {
        fvec4 v = ((const fvec4*)x)[i];
        float g = gate[i >> 10];     // 1024 float4 per (b,c) plane
        v *= g;
        __builtin_nontemporal_store(v, ((fvec4*)out) + i);
    }
}

extern "C" void kernel_launch(void* const* d_in, const int* in_sizes, int n_in,
                              void* d_out, int out_size, void* d_ws, size_t ws_size,
                              hipStream_t stream) {
    const float* x  = (const float*)d_in[0];
    const float* w1 = (const float*)d_in[1];
    const float* w2 = (const float*)d_in[2];
    float* out = (float*)d_out;

    float* spectral = (float*)d_ws;                         // B*C*F = 32768 floats
    float* gate     = (float*)d_ws + (size_t)B_ * C_ * F_;  // B*C   = 8192 floats

    spectral_kernel<<<B_ * C_, 256, 0, stream>>>(x, spectral);
    gate_kernel<<<B_, 256, 0, stream>>>(spectral, w1, w2, gate);

    const long long n4 = (long long)B_ * C_ * HW / 4;       // 8388608
    scale_kernel<<<2048, 256, 0, stream>>>(x, gate, out, n4);
}